// Round 7
// baseline (89.677 us; speedup 1.0000x reference)
//
#include <hip/hip_runtime.h>
#include <math.h>

#define Cc 96
#define Hh 128
#define Ww 128
#define HWsz (Hh*Ww)
#define TW 16
#define TH 8
#define LROW 18
#define LPLANE 180
#define CPAD 104      // ushort stride per position: 208B rows, 16B-aligned

typedef _Float16 h2 __attribute__((ext_vector_type(2)));

__device__ __forceinline__ unsigned pkrtz_u(float a, float b) {
    return __builtin_bit_cast(unsigned, __builtin_amdgcn_cvt_pkrtz(a, b));
}
__device__ __forceinline__ h2 pk2(float a, float b) {
    return __builtin_bit_cast(h2, __builtin_amdgcn_cvt_pkrtz(a, b));
}
__device__ __forceinline__ h2 u2h(unsigned u) { return __builtin_bit_cast(h2, u); }

#define GETW(v, wi) ((wi)==0 ? (v).x : (wi)==1 ? (v).y : (wi)==2 ? (v).z : (v).w)

// packed-weight layout in d_ws (dword offsets)
// [0, 576):   depthwise, [48 pair][12]: slot0 = (dw_b[2p],dw_b[2p+1]),
//             slots1..9 = (dw_w[2p][k],dw_w[2p+1][k]), slots10,11 pad (16B-aligned rows)
// OFF_PW1:    [48 o][48 p]  (pw1_w[o][2p], pw1_w[o][2p+1])  -- contiguous per o
// OFF_PW2:    [9 k][24 tp]  (pw2_w[k][2tp], pw2_w[k][2tp+1])
#define OFF_DW   0
#define OFF_PW1  576
#define OFF_PW2  2880
#define NPK      3096

__global__ void alpf_prep(const float* __restrict__ dw_w, const float* __restrict__ dw_b,
                          const float* __restrict__ pw1_w, const float* __restrict__ pw2_w,
                          unsigned* __restrict__ wpk)
{
    int i = blockIdx.x * 256 + threadIdx.x;
    if (i >= NPK) return;
    unsigned v;
    if (i < OFF_PW1) {
        int p = i / 12, r = i - 12 * p;
        if (r == 0)      v = pkrtz_u(dw_b[2*p], dw_b[2*p+1]);
        else if (r <= 9) v = pkrtz_u(dw_w[(2*p)*9 + (r-1)], dw_w[(2*p+1)*9 + (r-1)]);
        else             v = 0u;
    } else if (i < OFF_PW2) {
        int idx = i - OFF_PW1; int o = idx / 48, p = idx - 48*o;
        v = pkrtz_u(pw1_w[o*Cc + 2*p], pw1_w[o*Cc + 2*p+1]);
    } else {
        int idx = i - OFF_PW2; int k = idx / 24, p = idx - 24*k;
        v = pkrtz_u(pw2_w[k*48 + 2*p], pw2_w[k*48 + 2*p+1]);
    }
    wpk[i] = v;
}

__global__ __launch_bounds__(128, 2)
void alpf_fused(const float* __restrict__ x,
                const float* __restrict__ pw1_b,
                const float* __restrict__ pw2_b,
                const unsigned* __restrict__ wpk,
                float* __restrict__ out)
{
    __shared__ unsigned short lx[LPLANE * CPAD];   // 37440 B
    __shared__ unsigned wlds[576];                 // 2304 B depthwise-weight cache

    const int tid = threadIdx.x;
    const int x0 = blockIdx.x * TW;
    const int y0 = blockIdx.y * TH;
    const int b  = blockIdx.z;
    const float* __restrict__ xb = x + (size_t)b * Cc * HWsz;

    // ---- halo slot geometry ----
    const int e1 = tid;
    const int r1 = e1 / LROW, q1 = e1 - r1 * LROW;
    const int gy1 = y0 - 1 + r1, gx1 = x0 - 1 + q1;
    const bool ok1 = (gy1 >= 0) & (gy1 < Hh) & (gx1 >= 0) & (gx1 < Ww);
    const int g1 = gy1 * Ww + gx1;
    const int e2 = tid + 128;
    const bool v2 = (e2 < LPLANE);
    const int r2 = e2 / LROW, q2 = e2 - r2 * LROW;
    const int gy2 = y0 - 1 + r2, gx2 = x0 - 1 + q2;
    const bool ok2 = v2 & (gy2 >= 0) & (gy2 < Hh) & (gx2 >= 0) & (gx2 < Ww);
    const int g2 = gy2 * Ww + gx2;

    // ---- depthwise-weight cache: 576 dwords, 128 threads x uint4 + 16-thread tail ----
    *reinterpret_cast<uint4*>(&wlds[tid * 4]) =
        *reinterpret_cast<const uint4*>(wpk + tid * 4);            // dwords 0..511
    if (tid < 16)
        *reinterpret_cast<uint4*>(&wlds[512 + tid * 4]) =
            *reinterpret_cast<const uint4*>(wpk + 512 + tid * 4);  // dwords 512..575

    // ---- staging: f32 global -> fp16 LDS, layout [pos][chan] ----
    #pragma unroll 2
    for (int cg = 0; cg < 12; ++cg) {
        const int c0 = cg * 8;
        const float* xc = xb + (size_t)c0 * HWsz;
        {
            float v0 = ok1 ? xc[0*HWsz + g1] : 0.f;
            float v1 = ok1 ? xc[1*HWsz + g1] : 0.f;
            float v2_ = ok1 ? xc[2*HWsz + g1] : 0.f;
            float v3 = ok1 ? xc[3*HWsz + g1] : 0.f;
            float v4 = ok1 ? xc[4*HWsz + g1] : 0.f;
            float v5 = ok1 ? xc[5*HWsz + g1] : 0.f;
            float v6 = ok1 ? xc[6*HWsz + g1] : 0.f;
            float v7 = ok1 ? xc[7*HWsz + g1] : 0.f;
            *reinterpret_cast<uint4*>(&lx[e1 * CPAD + c0]) =
                make_uint4(pkrtz_u(v0,v1), pkrtz_u(v2_,v3), pkrtz_u(v4,v5), pkrtz_u(v6,v7));
        }
        if (v2) {
            float v0 = ok2 ? xc[0*HWsz + g2] : 0.f;
            float v1 = ok2 ? xc[1*HWsz + g2] : 0.f;
            float v2_ = ok2 ? xc[2*HWsz + g2] : 0.f;
            float v3 = ok2 ? xc[3*HWsz + g2] : 0.f;
            float v4 = ok2 ? xc[4*HWsz + g2] : 0.f;
            float v5 = ok2 ? xc[5*HWsz + g2] : 0.f;
            float v6 = ok2 ? xc[6*HWsz + g2] : 0.f;
            float v7 = ok2 ? xc[7*HWsz + g2] : 0.f;
            *reinterpret_cast<uint4*>(&lx[e2 * CPAD + c0]) =
                make_uint4(pkrtz_u(v0,v1), pkrtz_u(v2_,v3), pkrtz_u(v4,v5), pkrtz_u(v6,v7));
        }
    }
    __syncthreads();

    // ---- per-pixel mapping ----
    const int lane = tid & 63;
    const int sx = lane & 15;
    const int sy = (lane >> 4) + ((tid >> 6) << 2);
    const unsigned short* lb = &lx[(sy * LROW + sx) * CPAD];

    // ---- phase A (DS-only): depthwise 3x3 for all 96 channels -> hc[48] h2 ----
    h2 hc[48];
    #pragma unroll
    for (int cg = 0; cg < 12; ++cg) {
        const int c0 = cg * 8;
        uint4 tp[9];
        #pragma unroll
        for (int k = 0; k < 9; ++k) {
            const int dy = k / 3, dx = k - 3 * dy;
            tp[k] = *reinterpret_cast<const uint4*>(&lb[(dy*LROW+dx)*CPAD + c0]);
        }
        #pragma unroll
        for (int l = 0; l < 4; ++l) {
            const int li = cg * 4 + l;
            const uint4 wA = *reinterpret_cast<const uint4*>(&wlds[li*12]);      // dwb, dww0..2
            const uint4 wB = *reinterpret_cast<const uint4*>(&wlds[li*12 + 4]);  // dww3..6
            const uint2 wC = *reinterpret_cast<const uint2*>(&wlds[li*12 + 8]);  // dww7..8
            h2 acc = u2h(wA.x);
            acc = __builtin_elementwise_fma(u2h(GETW(tp[0], l)), u2h(wA.y), acc);
            acc = __builtin_elementwise_fma(u2h(GETW(tp[1], l)), u2h(wA.z), acc);
            acc = __builtin_elementwise_fma(u2h(GETW(tp[2], l)), u2h(wA.w), acc);
            acc = __builtin_elementwise_fma(u2h(GETW(tp[3], l)), u2h(wB.x), acc);
            acc = __builtin_elementwise_fma(u2h(GETW(tp[4], l)), u2h(wB.y), acc);
            acc = __builtin_elementwise_fma(u2h(GETW(tp[5], l)), u2h(wB.z), acc);
            acc = __builtin_elementwise_fma(u2h(GETW(tp[6], l)), u2h(wB.w), acc);
            acc = __builtin_elementwise_fma(u2h(GETW(tp[7], l)), u2h(wC.x), acc);
            acc = __builtin_elementwise_fma(u2h(GETW(tp[8], l)), u2h(wC.y), acc);
            hc[li] = acc;
        }
    }

    // ---- phase B (SMEM-only): pw1 as one contiguous scalar weight stream ----
    float t[48];
    #pragma unroll
    for (int o = 0; o < 48; ++o) {
        float s = pw1_b[o];
        #pragma unroll
        for (int p = 0; p < 48; ++p)
            s = __builtin_amdgcn_fdot2(hc[p], u2h(wpk[OFF_PW1 + o*48 + p]), s, false);
        t[o] = s;
    }

    // ---- LeakyReLU + pack -> pw2 (dot2, contiguous scalar stream) ----
    #pragma unroll
    for (int o = 0; o < 48; ++o) { float v = t[o]; t[o] = (v >= 0.f) ? v : 0.2f * v; }
    h2 tp2[24];
    #pragma unroll
    for (int p = 0; p < 24; ++p)
        tp2[p] = pk2(t[2*p], t[2*p+1]);
    float kw[9];
    #pragma unroll
    for (int k = 0; k < 9; ++k) {
        float s = pw2_b[k];
        #pragma unroll
        for (int p = 0; p < 24; ++p)
            s = __builtin_amdgcn_fdot2(tp2[p], u2h(wpk[OFF_PW2 + k*24 + p]), s, false);
        kw[k] = s;
    }

    // ---- softmax over 9 ----
    float m = kw[0];
    #pragma unroll
    for (int k = 1; k < 9; ++k) m = fmaxf(m, kw[k]);
    float s = 0.f;
    #pragma unroll
    for (int k = 0; k < 9; ++k) { kw[k] = __expf(kw[k] - m); s += kw[k]; }
    const float inv = 1.f / s;
    h2 kwp[9];
    #pragma unroll
    for (int k = 0; k < 9; ++k) { kw[k] *= inv; kwp[k] = pk2(kw[k], kw[k]); }

    // ---- pass 2 (DS-only): smoothing from the resident LDS tile ----
    float* __restrict__ ob = out + (size_t)b * Cc * HWsz + (size_t)(y0 + sy) * Ww + (x0 + sx);
    #pragma unroll 2
    for (int cg = 0; cg < 12; ++cg) {
        const int c0 = cg * 8;
        uint4 tp[9];
        #pragma unroll
        for (int k = 0; k < 9; ++k) {
            const int dy = k / 3, dx = k - 3 * dy;
            tp[k] = *reinterpret_cast<const uint4*>(&lb[(dy*LROW+dx)*CPAD + c0]);
        }
        #pragma unroll
        for (int l = 0; l < 4; ++l) {
            h2 a0 = u2h(GETW(tp[0], l)) * kwp[0];
            h2 a1 = u2h(GETW(tp[1], l)) * kwp[1];
            h2 a2 = u2h(GETW(tp[2], l)) * kwp[2];
            a0 = __builtin_elementwise_fma(u2h(GETW(tp[3], l)), kwp[3], a0);
            a1 = __builtin_elementwise_fma(u2h(GETW(tp[4], l)), kwp[4], a1);
            a2 = __builtin_elementwise_fma(u2h(GETW(tp[5], l)), kwp[5], a2);
            a0 = __builtin_elementwise_fma(u2h(GETW(tp[6], l)), kwp[6], a0);
            a1 = __builtin_elementwise_fma(u2h(GETW(tp[7], l)), kwp[7], a1);
            a2 = __builtin_elementwise_fma(u2h(GETW(tp[8], l)), kwp[8], a2);
            float olo = (float)a0.x + (float)a1.x + (float)a2.x;
            float ohi = (float)a0.y + (float)a1.y + (float)a2.y;
            ob[(size_t)(c0 + 2*l)     * HWsz] = olo;
            ob[(size_t)(c0 + 2*l + 1) * HWsz] = ohi;
        }
    }
}

extern "C" void kernel_launch(void* const* d_in, const int* in_sizes, int n_in,
                              void* d_out, int out_size, void* d_ws, size_t ws_size,
                              hipStream_t stream)
{
    const float* x     = (const float*)d_in[0];
    const float* dw_w  = (const float*)d_in[1];
    const float* dw_b  = (const float*)d_in[2];
    const float* pw1_w = (const float*)d_in[3];
    const float* pw1_b = (const float*)d_in[4];
    const float* pw2_w = (const float*)d_in[5];
    const float* pw2_b = (const float*)d_in[6];
    float* outp = (float*)d_out;
    unsigned* wpk = (unsigned*)d_ws;

    alpf_prep<<<(NPK + 255) / 256, 256, 0, stream>>>(dw_w, dw_b, pw1_w, pw2_w, wpk);

    const int B = in_sizes[0] / (Cc * HWsz);   // 8
    dim3 grid(Ww / TW, Hh / TH, B);
    alpf_fused<<<grid, 128, 0, stream>>>(x, pw1_b, pw2_b, wpk, outp);
}

// Round 8
// 52.515 us; speedup vs baseline: 1.7076x; 1.7076x over previous
//
#include <hip/hip_runtime.h>
#include <math.h>

#define Cc 96
#define Hh 128
#define Ww 128
#define HWsz (Hh*Ww)
#define TW 16
#define TH 8
#define LROW 18
#define LPLANE 180
#define CPAD 104      // ushort stride per position: 208B rows, 16B-aligned

typedef _Float16 h2 __attribute__((ext_vector_type(2)));
typedef short    s8v __attribute__((ext_vector_type(8)));   // 8 bf16 (MFMA A/B frag)
typedef float    f4v __attribute__((ext_vector_type(4)));   // MFMA C/D frag

__device__ __forceinline__ unsigned pkrtz_u(float a, float b) {
    return __builtin_bit_cast(unsigned, __builtin_amdgcn_cvt_pkrtz(a, b));
}
__device__ __forceinline__ h2 pk2(float a, float b) {
    return __builtin_bit_cast(h2, __builtin_amdgcn_cvt_pkrtz(a, b));
}
__device__ __forceinline__ h2 u2h(unsigned u) { return __builtin_bit_cast(h2, u); }
__device__ __forceinline__ unsigned cvt_pk_bf16(float lo, float hi) {
    unsigned r;
    asm("v_cvt_pk_bf16_f32 %0, %1, %2" : "=v"(r) : "v"(lo), "v"(hi));
    return r;
}

__host__ __device__ __forceinline__ unsigned f2bf(float f) {   // fp32 -> bf16 RNE
    unsigned u = __float_as_uint(f);
    return (u + 0x7fffu + ((u >> 16) & 1u)) >> 16;
}

#define GETW(v, wi) ((wi)==0 ? (v).x : (wi)==1 ? (v).y : (wi)==2 ? (v).z : (v).w)

// ---- d_ws layout (dword offsets) ----
// OFF_WDW [0,480):   depthwise f16 pairs, [g:4][ks:3][40]:
//                    slot 0..3 = bias pairs ch=32ks+8g+2d; slot 4+4t+d = tap t, pair d
// OFF_W2  [480,704): pw2 f16 pairs, [g:4][56]: idx k*6+2m+rp -> (pw2[k][16m+4g+2rp], +1); 54,55 pad
// OFF_P1B [704,752): pw1_b raw f32 [48]
// OFF_A   [768,3072): W1 bf16 A-frags, [f=m*3+ks:9][lane:64][d:4]:
//                    halves = W1[o=16m+(l&15)][ch=32ks+8(l>>4)+2d], +1
#define OFF_WDW 0
#define OFF_W2  480
#define OFF_P1B 704
#define OFF_A   768
#define NPK     3072
#define WLDS_N  752

__global__ void alpf_prep(const float* __restrict__ dw_w, const float* __restrict__ dw_b,
                          const float* __restrict__ pw1_w, const float* __restrict__ pw1_b,
                          const float* __restrict__ pw2_w, unsigned* __restrict__ wpk)
{
    int i = blockIdx.x * 256 + threadIdx.x;
    if (i >= NPK) return;
    unsigned v = 0u;
    if (i < OFF_W2) {
        int g = i / 120, rem = i % 120, ks = rem / 40, s = rem % 40;
        int chb = 32*ks + 8*g;
        if (s < 4) v = pkrtz_u(dw_b[chb + 2*s], dw_b[chb + 2*s + 1]);
        else { int t = (s - 4) / 4, d = (s - 4) % 4;
               v = pkrtz_u(dw_w[(chb + 2*d)*9 + t], dw_w[(chb + 2*d + 1)*9 + t]); }
    } else if (i < OFF_P1B) {
        int idx = i - OFF_W2; int g = idx / 56, s = idx % 56;
        if (s < 54) { int k = s / 6, mm = s % 6, m = mm / 2, rp = mm % 2;
            int o = 16*m + 4*g + 2*rp;
            v = pkrtz_u(pw2_w[k*48 + o], pw2_w[k*48 + o + 1]); }
    } else if (i < OFF_P1B + 48) {
        v = __float_as_uint(pw1_b[i - OFF_P1B]);
    } else if (i >= OFF_A) {
        int idx = i - OFF_A; int f = idx / 256, rem = idx % 256, l = rem / 4, d = rem % 4;
        int m = f / 3, ks = f % 3;
        int o  = 16*m + (l & 15);
        int ch = 32*ks + 8*(l >> 4) + 2*d;
        v = f2bf(pw1_w[o*Cc + ch]) | (f2bf(pw1_w[o*Cc + ch + 1]) << 16);
    }
    wpk[i] = v;
}

__global__ __launch_bounds__(128, 2)
void alpf_fused(const float* __restrict__ x,
                const float* __restrict__ pw2_b,
                const unsigned* __restrict__ wpk,
                float* __restrict__ out)
{
    __shared__ unsigned short lx[LPLANE * CPAD];   // 37440 B
    __shared__ unsigned wlds[WLDS_N];              // 3008 B weight cache

    const int tid = threadIdx.x;
    const int x0 = blockIdx.x * TW;
    const int y0 = blockIdx.y * TH;
    const int b  = blockIdx.z;
    const float* __restrict__ xb = x + (size_t)b * Cc * HWsz;

    // ---- weight cache copy (752 dwords) ----
    *reinterpret_cast<uint4*>(&wlds[tid * 4]) =
        *reinterpret_cast<const uint4*>(wpk + tid * 4);            // 0..511
    if (tid < 60)
        *reinterpret_cast<uint4*>(&wlds[512 + tid * 4]) =
            *reinterpret_cast<const uint4*>(wpk + 512 + tid * 4);  // 512..751

    const int lane = tid & 63;
    const int g    = lane >> 4;
    const int c15  = lane & 15;
    const int w    = tid >> 6;

    // ---- resident W1 A-fragments (loaded once, 36 VGPRs) ----
    s8v Af[9];
    #pragma unroll
    for (int f = 0; f < 9; ++f)
        Af[f] = __builtin_bit_cast(s8v,
            *reinterpret_cast<const uint4*>(wpk + OFF_A + (f*64 + lane)*4));

    // ---- halo slot geometry ----
    const int e1 = tid;
    const int r1 = e1 / LROW, q1 = e1 - r1 * LROW;
    const int gy1 = y0 - 1 + r1, gx1 = x0 - 1 + q1;
    const bool ok1 = (gy1 >= 0) & (gy1 < Hh) & (gx1 >= 0) & (gx1 < Ww);
    const int g1 = gy1 * Ww + gx1;
    const int e2 = tid + 128;
    const bool v2 = (e2 < LPLANE);
    const int r2 = e2 / LROW, q2 = e2 - r2 * LROW;
    const int gy2 = y0 - 1 + r2, gx2 = x0 - 1 + q2;
    const bool ok2 = v2 & (gy2 >= 0) & (gy2 < Hh) & (gx2 >= 0) & (gx2 < Ww);
    const int g2 = gy2 * Ww + gx2;

    // ---- staging: f32 global -> fp16 LDS, layout [pos][chan] ----
    #pragma unroll 2
    for (int cg = 0; cg < 12; ++cg) {
        const int c0 = cg * 8;
        const float* xc = xb + (size_t)c0 * HWsz;
        {
            float v0 = ok1 ? xc[0*HWsz + g1] : 0.f;
            float v1 = ok1 ? xc[1*HWsz + g1] : 0.f;
            float v2_ = ok1 ? xc[2*HWsz + g1] : 0.f;
            float v3 = ok1 ? xc[3*HWsz + g1] : 0.f;
            float v4 = ok1 ? xc[4*HWsz + g1] : 0.f;
            float v5 = ok1 ? xc[5*HWsz + g1] : 0.f;
            float v6 = ok1 ? xc[6*HWsz + g1] : 0.f;
            float v7 = ok1 ? xc[7*HWsz + g1] : 0.f;
            *reinterpret_cast<uint4*>(&lx[e1 * CPAD + c0]) =
                make_uint4(pkrtz_u(v0,v1), pkrtz_u(v2_,v3), pkrtz_u(v4,v5), pkrtz_u(v6,v7));
        }
        if (v2) {
            float v0 = ok2 ? xc[0*HWsz + g2] : 0.f;
            float v1 = ok2 ? xc[1*HWsz + g2] : 0.f;
            float v2_ = ok2 ? xc[2*HWsz + g2] : 0.f;
            float v3 = ok2 ? xc[3*HWsz + g2] : 0.f;
            float v4 = ok2 ? xc[4*HWsz + g2] : 0.f;
            float v5 = ok2 ? xc[5*HWsz + g2] : 0.f;
            float v6 = ok2 ? xc[6*HWsz + g2] : 0.f;
            float v7 = ok2 ? xc[7*HWsz + g2] : 0.f;
            *reinterpret_cast<uint4*>(&lx[e2 * CPAD + c0]) =
                make_uint4(pkrtz_u(v0,v1), pkrtz_u(v2_,v3), pkrtz_u(v4,v5), pkrtz_u(v6,v7));
        }
    }
    __syncthreads();

    // ---- pw1 bias -> accumulators (D rows: o = 16m + 4g + r) ----
    f4v acc[3][4];
    #pragma unroll
    for (int m = 0; m < 3; ++m) {
        const f4v bb = *reinterpret_cast<const f4v*>(&wlds[OFF_P1B + 16*m + 4*g]);
        #pragma unroll
        for (int n = 0; n < 4; ++n) acc[m][n] = bb;
    }

    // ---- depthwise conv (f16) -> bf16 B-frags -> MFMA pw1 ----
    #pragma unroll
    for (int ks = 0; ks < 3; ++ks) {
        const int base = (g*3 + ks) * 40;
        const uint4 wb = *reinterpret_cast<const uint4*>(&wlds[base]);
        uint4 wt[9];
        #pragma unroll
        for (int t = 0; t < 9; ++t)
            wt[t] = *reinterpret_cast<const uint4*>(&wlds[base + 4 + 4*t]);
        #pragma unroll
        for (int n = 0; n < 4; ++n) {
            h2 b0 = u2h(wb.x), b1 = u2h(wb.y), b2 = u2h(wb.z), b3 = u2h(wb.w);
            #pragma unroll
            for (int t = 0; t < 9; ++t) {
                const int dy = t / 3, dx = t - 3*dy;
                const uint4 xv = *reinterpret_cast<const uint4*>(
                    &lx[((4*w + n + dy)*LROW + c15 + dx)*CPAD + 32*ks + 8*g]);
                b0 = __builtin_elementwise_fma(u2h(xv.x), u2h(wt[t].x), b0);
                b1 = __builtin_elementwise_fma(u2h(xv.y), u2h(wt[t].y), b1);
                b2 = __builtin_elementwise_fma(u2h(xv.z), u2h(wt[t].z), b2);
                b3 = __builtin_elementwise_fma(u2h(xv.w), u2h(wt[t].w), b3);
            }
            uint4 bq;
            bq.x = cvt_pk_bf16((float)b0.x, (float)b0.y);
            bq.y = cvt_pk_bf16((float)b1.x, (float)b1.y);
            bq.z = cvt_pk_bf16((float)b2.x, (float)b2.y);
            bq.w = cvt_pk_bf16((float)b3.x, (float)b3.y);
            const s8v Bf = __builtin_bit_cast(s8v, bq);
            acc[0][n] = __builtin_amdgcn_mfma_f32_16x16x32_bf16(Af[0 + ks], Bf, acc[0][n], 0, 0, 0);
            acc[1][n] = __builtin_amdgcn_mfma_f32_16x16x32_bf16(Af[3 + ks], Bf, acc[1][n], 0, 0, 0);
            acc[2][n] = __builtin_amdgcn_mfma_f32_16x16x32_bf16(Af[6 + ks], Bf, acc[2][n], 0, 0, 0);
        }
    }

    // ---- LeakyReLU + pack t to f16 pairs (o = 16m+4g+2rp, +1) ----
    h2 tpk[4][3][2];
    #pragma unroll
    for (int n = 0; n < 4; ++n)
        #pragma unroll
        for (int m = 0; m < 3; ++m)
            #pragma unroll
            for (int rp = 0; rp < 2; ++rp) {
                float a = acc[m][n][2*rp], c = acc[m][n][2*rp + 1];
                a = (a >= 0.f) ? a : 0.2f * a;
                c = (c >= 0.f) ? c : 0.2f * c;
                tpk[n][m][rp] = pk2(a, c);
            }

    // ---- pw2 partials (this lane's o-slice), then butterfly over g ----
    uint4 w2q[14];
    #pragma unroll
    for (int j = 0; j < 14; ++j)
        w2q[j] = *reinterpret_cast<const uint4*>(&wlds[OFF_W2 + g*56 + 4*j]);

    float kwr[4][9];
    #pragma unroll
    for (int k = 0; k < 9; ++k) {
        #pragma unroll
        for (int n = 0; n < 4; ++n) {
            h2 s = pk2(0.f, 0.f);
            #pragma unroll
            for (int m = 0; m < 3; ++m)
                #pragma unroll
                for (int rp = 0; rp < 2; ++rp) {
                    const int d = k*6 + 2*m + rp;
                    s = __builtin_elementwise_fma(tpk[n][m][rp],
                                                  u2h(GETW(w2q[d >> 2], d & 3)), s);
                }
            kwr[n][k] = (float)s.x + (float)s.y;
        }
    }
    #pragma unroll
    for (int n = 0; n < 4; ++n)
        #pragma unroll
        for (int k = 0; k < 9; ++k) {
            float v = kwr[n][k];
            v += __shfl_xor(v, 16);
            v += __shfl_xor(v, 32);
            kwr[n][k] = v + pw2_b[k];
        }

    // lane keeps slice n == g  ->  kw[9] for pixel 16g + c15 (+64w)
    float kw[9];
    #pragma unroll
    for (int k = 0; k < 9; ++k)
        kw[k] = (g == 0) ? kwr[0][k] : (g == 1) ? kwr[1][k] : (g == 2) ? kwr[2][k] : kwr[3][k];

    // ---- softmax over 9 ----
    float mx = kw[0];
    #pragma unroll
    for (int k = 1; k < 9; ++k) mx = fmaxf(mx, kw[k]);
    float sum = 0.f;
    #pragma unroll
    for (int k = 0; k < 9; ++k) { kw[k] = __expf(kw[k] - mx); sum += kw[k]; }
    const float inv = 1.f / sum;
    h2 kwp[9];
    #pragma unroll
    for (int k = 0; k < 9; ++k) { kw[k] *= inv; kwp[k] = pk2(kw[k], kw[k]); }

    // ---- pass 2: smoothing from the resident LDS tile ----
    const int sx = c15;
    const int sy = g + 4*w;
    const unsigned short* lb = &lx[(sy * LROW + sx) * CPAD];
    float* __restrict__ ob = out + (size_t)b * Cc * HWsz + (size_t)(y0 + sy) * Ww + (x0 + sx);
    #pragma unroll 2
    for (int cg = 0; cg < 12; ++cg) {
        const int c0 = cg * 8;
        uint4 tp[9];
        #pragma unroll
        for (int k = 0; k < 9; ++k) {
            const int dy = k / 3, dx = k - 3 * dy;
            tp[k] = *reinterpret_cast<const uint4*>(&lb[(dy*LROW + dx)*CPAD + c0]);
        }
        #pragma unroll
        for (int l = 0; l < 4; ++l) {
            h2 a0 = u2h(GETW(tp[0], l)) * kwp[0];
            h2 a1 = u2h(GETW(tp[1], l)) * kwp[1];
            h2 a2 = u2h(GETW(tp[2], l)) * kwp[2];
            a0 = __builtin_elementwise_fma(u2h(GETW(tp[3], l)), kwp[3], a0);
            a1 = __builtin_elementwise_fma(u2h(GETW(tp[4], l)), kwp[4], a1);
            a2 = __builtin_elementwise_fma(u2h(GETW(tp[5], l)), kwp[5], a2);
            a0 = __builtin_elementwise_fma(u2h(GETW(tp[6], l)), kwp[6], a0);
            a1 = __builtin_elementwise_fma(u2h(GETW(tp[7], l)), kwp[7], a1);
            a2 = __builtin_elementwise_fma(u2h(GETW(tp[8], l)), kwp[8], a2);
            float olo = (float)a0.x + (float)a1.x + (float)a2.x;
            float ohi = (float)a0.y + (float)a1.y + (float)a2.y;
            ob[(size_t)(c0 + 2*l)     * HWsz] = olo;
            ob[(size_t)(c0 + 2*l + 1) * HWsz] = ohi;
        }
    }
}

extern "C" void kernel_launch(void* const* d_in, const int* in_sizes, int n_in,
                              void* d_out, int out_size, void* d_ws, size_t ws_size,
                              hipStream_t stream)
{
    const float* x     = (const float*)d_in[0];
    const float* dw_w  = (const float*)d_in[1];
    const float* dw_b  = (const float*)d_in[2];
    const float* pw1_w = (const float*)d_in[3];
    const float* pw1_b = (const float*)d_in[4];
    const float* pw2_w = (const float*)d_in[5];
    const float* pw2_b = (const float*)d_in[6];
    float* outp = (float*)d_out;
    unsigned* wpk = (unsigned*)d_ws;

    alpf_prep<<<(NPK + 255) / 256, 256, 0, stream>>>(dw_w, dw_b, pw1_w, pw1_b, pw2_w, wpk);

    const int B = in_sizes[0] / (Cc * HWsz);   // 8
    dim3 grid(Ww / TW, Hh / TH, B);
    alpf_fused<<<grid, 128, 0, stream>>>(x, pw2_b, wpk, outp);
}

// Round 9
// 39.140 us; speedup vs baseline: 2.2912x; 1.3417x over previous
//
#include <hip/hip_runtime.h>
#include <math.h>

#define Cc 96
#define Hh 128
#define Ww 128
#define HWsz (Hh*Ww)
#define TW 16
#define TH 8
#define LROW 18
#define LPLANE 180
#define CPAD 104      // ushort stride per position: 208B rows, 16B-aligned

typedef _Float16 h2 __attribute__((ext_vector_type(2)));
typedef short    s8v __attribute__((ext_vector_type(8)));   // 8 bf16 (MFMA A/B frag)
typedef float    f4v __attribute__((ext_vector_type(4)));   // MFMA C/D frag

__device__ __forceinline__ unsigned pkrtz_u(float a, float b) {
    return __builtin_bit_cast(unsigned, __builtin_amdgcn_cvt_pkrtz(a, b));
}
__device__ __forceinline__ h2 pk2(float a, float b) {
    return __builtin_bit_cast(h2, __builtin_amdgcn_cvt_pkrtz(a, b));
}
__device__ __forceinline__ h2 u2h(unsigned u) { return __builtin_bit_cast(h2, u); }
__device__ __forceinline__ unsigned cvt_pk_bf16(float lo, float hi) {
    unsigned r;
    asm("v_cvt_pk_bf16_f32 %0, %1, %2" : "=v"(r) : "v"(lo), "v"(hi));
    return r;
}

__host__ __device__ __forceinline__ unsigned f2bf(float f) {   // fp32 -> bf16 RNE
    unsigned u = __float_as_uint(f);
    return (u + 0x7fffu + ((u >> 16) & 1u)) >> 16;
}

#define GETW(v, wi) ((wi)==0 ? (v).x : (wi)==1 ? (v).y : (wi)==2 ? (v).z : (v).w)

// ---- d_ws layout (dword offsets) ----
#define OFF_WDW 0
#define OFF_W2  480
#define OFF_P1B 704
#define OFF_A   768
#define NPK     3072
#define WLDS_N  752

__global__ void alpf_prep(const float* __restrict__ dw_w, const float* __restrict__ dw_b,
                          const float* __restrict__ pw1_w, const float* __restrict__ pw1_b,
                          const float* __restrict__ pw2_w, unsigned* __restrict__ wpk)
{
    int i = blockIdx.x * 256 + threadIdx.x;
    if (i >= NPK) return;
    unsigned v = 0u;
    if (i < OFF_W2) {
        int g = i / 120, rem = i % 120, ks = rem / 40, s = rem % 40;
        int chb = 32*ks + 8*g;
        if (s < 4) v = pkrtz_u(dw_b[chb + 2*s], dw_b[chb + 2*s + 1]);
        else { int t = (s - 4) / 4, d = (s - 4) % 4;
               v = pkrtz_u(dw_w[(chb + 2*d)*9 + t], dw_w[(chb + 2*d + 1)*9 + t]); }
    } else if (i < OFF_P1B) {
        int idx = i - OFF_W2; int g = idx / 56, s = idx % 56;
        if (s < 54) { int k = s / 6, mm = s % 6, m = mm / 2, rp = mm % 2;
            int o = 16*m + 4*g + 2*rp;
            v = pkrtz_u(pw2_w[k*48 + o], pw2_w[k*48 + o + 1]); }
    } else if (i < OFF_P1B + 48) {
        v = __float_as_uint(pw1_b[i - OFF_P1B]);
    } else if (i >= OFF_A) {
        int idx = i - OFF_A; int f = idx / 256, rem = idx % 256, l = rem / 4, d = rem % 4;
        int m = f / 3, ks = f % 3;
        int o  = 16*m + (l & 15);
        int ch = 32*ks + 8*(l >> 4) + 2*d;
        v = f2bf(pw1_w[o*Cc + ch]) | (f2bf(pw1_w[o*Cc + ch + 1]) << 16);
    }
    wpk[i] = v;
}

__global__ __launch_bounds__(128, 2)
void alpf_fused(const float* __restrict__ x,
                const float* __restrict__ pw2_b,
                const unsigned* __restrict__ wpk,
                float* __restrict__ out)
{
    __shared__ unsigned short lx[LPLANE * CPAD];   // 37440 B
    __shared__ unsigned wlds[WLDS_N];              // 3008 B weight cache

    const int tid = threadIdx.x;

    // ---- XCD-chunked swizzle: each XCD gets a contiguous run of tiles ----
    // hw dispatch is round-robin over 8 XCDs; remap so XCD k owns logical
    // tiles [k*nwg/8, (k+1)*nwg/8) -> halo-sharing neighbors co-reside in L2.
    const int nwg   = gridDim.x;            // 1024, divisible by 8 -> bijective
    const int chunk = nwg >> 3;
    const int logical = (blockIdx.x & 7) * chunk + (blockIdx.x >> 3);
    const int tx = logical & 7;             // 8 tiles in x
    const int ty = (logical >> 3) & 15;     // 16 tiles in y
    const int b  = logical >> 7;            // batch
    const int x0 = tx * TW;
    const int y0 = ty * TH;
    const float* __restrict__ xb = x + (size_t)b * Cc * HWsz;

    // ---- weight cache copy (752 dwords) ----
    *reinterpret_cast<uint4*>(&wlds[tid * 4]) =
        *reinterpret_cast<const uint4*>(wpk + tid * 4);            // 0..511
    if (tid < 60)
        *reinterpret_cast<uint4*>(&wlds[512 + tid * 4]) =
            *reinterpret_cast<const uint4*>(wpk + 512 + tid * 4);  // 512..751

    const int lane = tid & 63;
    const int g    = lane >> 4;
    const int c15  = lane & 15;
    const int w    = tid >> 6;

    // ---- resident W1 A-fragments (loaded once, 36 VGPRs) ----
    s8v Af[9];
    #pragma unroll
    for (int f = 0; f < 9; ++f)
        Af[f] = __builtin_bit_cast(s8v,
            *reinterpret_cast<const uint4*>(wpk + OFF_A + (f*64 + lane)*4));

    // ---- halo slot geometry ----
    const int e1 = tid;
    const int r1 = e1 / LROW, q1 = e1 - r1 * LROW;
    const int gy1 = y0 - 1 + r1, gx1 = x0 - 1 + q1;
    const bool ok1 = (gy1 >= 0) & (gy1 < Hh) & (gx1 >= 0) & (gx1 < Ww);
    const int g1 = gy1 * Ww + gx1;
    const int e2 = tid + 128;
    const bool v2 = (e2 < LPLANE);
    const int r2 = e2 / LROW, q2 = e2 - r2 * LROW;
    const int gy2 = y0 - 1 + r2, gx2 = x0 - 1 + q2;
    const bool ok2 = v2 & (gy2 >= 0) & (gy2 < Hh) & (gx2 >= 0) & (gx2 < Ww);
    const int g2 = gy2 * Ww + gx2;

    // ---- staging: f32 global -> fp16 LDS, layout [pos][chan] ----
    #pragma unroll 2
    for (int cg = 0; cg < 12; ++cg) {
        const int c0 = cg * 8;
        const float* xc = xb + (size_t)c0 * HWsz;
        {
            float v0 = ok1 ? xc[0*HWsz + g1] : 0.f;
            float v1 = ok1 ? xc[1*HWsz + g1] : 0.f;
            float v2_ = ok1 ? xc[2*HWsz + g1] : 0.f;
            float v3 = ok1 ? xc[3*HWsz + g1] : 0.f;
            float v4 = ok1 ? xc[4*HWsz + g1] : 0.f;
            float v5 = ok1 ? xc[5*HWsz + g1] : 0.f;
            float v6 = ok1 ? xc[6*HWsz + g1] : 0.f;
            float v7 = ok1 ? xc[7*HWsz + g1] : 0.f;
            *reinterpret_cast<uint4*>(&lx[e1 * CPAD + c0]) =
                make_uint4(pkrtz_u(v0,v1), pkrtz_u(v2_,v3), pkrtz_u(v4,v5), pkrtz_u(v6,v7));
        }
        if (v2) {
            float v0 = ok2 ? xc[0*HWsz + g2] : 0.f;
            float v1 = ok2 ? xc[1*HWsz + g2] : 0.f;
            float v2_ = ok2 ? xc[2*HWsz + g2] : 0.f;
            float v3 = ok2 ? xc[3*HWsz + g2] : 0.f;
            float v4 = ok2 ? xc[4*HWsz + g2] : 0.f;
            float v5 = ok2 ? xc[5*HWsz + g2] : 0.f;
            float v6 = ok2 ? xc[6*HWsz + g2] : 0.f;
            float v7 = ok2 ? xc[7*HWsz + g2] : 0.f;
            *reinterpret_cast<uint4*>(&lx[e2 * CPAD + c0]) =
                make_uint4(pkrtz_u(v0,v1), pkrtz_u(v2_,v3), pkrtz_u(v4,v5), pkrtz_u(v6,v7));
        }
    }
    __syncthreads();

    // ---- pw1 bias -> accumulators (D rows: o = 16m + 4g + r) ----
    f4v acc[3][4];
    #pragma unroll
    for (int m = 0; m < 3; ++m) {
        const f4v bb = *reinterpret_cast<const f4v*>(&wlds[OFF_P1B + 16*m + 4*g]);
        #pragma unroll
        for (int n = 0; n < 4; ++n) acc[m][n] = bb;
    }

    // ---- depthwise conv (f16) -> bf16 B-frags -> MFMA pw1 ----
    #pragma unroll
    for (int ks = 0; ks < 3; ++ks) {
        const int base = (g*3 + ks) * 40;
        const uint4 wb = *reinterpret_cast<const uint4*>(&wlds[base]);
        uint4 wt[9];
        #pragma unroll
        for (int t = 0; t < 9; ++t)
            wt[t] = *reinterpret_cast<const uint4*>(&wlds[base + 4 + 4*t]);
        #pragma unroll
        for (int n = 0; n < 4; ++n) {
            h2 b0 = u2h(wb.x), b1 = u2h(wb.y), b2 = u2h(wb.z), b3 = u2h(wb.w);
            #pragma unroll
            for (int t = 0; t < 9; ++t) {
                const int dy = t / 3, dx = t - 3*dy;
                const uint4 xv = *reinterpret_cast<const uint4*>(
                    &lx[((4*w + n + dy)*LROW + c15 + dx)*CPAD + 32*ks + 8*g]);
                b0 = __builtin_elementwise_fma(u2h(xv.x), u2h(wt[t].x), b0);
                b1 = __builtin_elementwise_fma(u2h(xv.y), u2h(wt[t].y), b1);
                b2 = __builtin_elementwise_fma(u2h(xv.z), u2h(wt[t].z), b2);
                b3 = __builtin_elementwise_fma(u2h(xv.w), u2h(wt[t].w), b3);
            }
            uint4 bq;
            bq.x = cvt_pk_bf16((float)b0.x, (float)b0.y);
            bq.y = cvt_pk_bf16((float)b1.x, (float)b1.y);
            bq.z = cvt_pk_bf16((float)b2.x, (float)b2.y);
            bq.w = cvt_pk_bf16((float)b3.x, (float)b3.y);
            const s8v Bf = __builtin_bit_cast(s8v, bq);
            acc[0][n] = __builtin_amdgcn_mfma_f32_16x16x32_bf16(Af[0 + ks], Bf, acc[0][n], 0, 0, 0);
            acc[1][n] = __builtin_amdgcn_mfma_f32_16x16x32_bf16(Af[3 + ks], Bf, acc[1][n], 0, 0, 0);
            acc[2][n] = __builtin_amdgcn_mfma_f32_16x16x32_bf16(Af[6 + ks], Bf, acc[2][n], 0, 0, 0);
        }
    }

    // ---- LeakyReLU + pack t to f16 pairs (o = 16m+4g+2rp, +1) ----
    h2 tpk[4][3][2];
    #pragma unroll
    for (int n = 0; n < 4; ++n)
        #pragma unroll
        for (int m = 0; m < 3; ++m)
            #pragma unroll
            for (int rp = 0; rp < 2; ++rp) {
                float a = acc[m][n][2*rp], c = acc[m][n][2*rp + 1];
                a = (a >= 0.f) ? a : 0.2f * a;
                c = (c >= 0.f) ? c : 0.2f * c;
                tpk[n][m][rp] = pk2(a, c);
            }

    // ---- pw2 partials (this lane's o-slice), then butterfly over g ----
    uint4 w2q[14];
    #pragma unroll
    for (int j = 0; j < 14; ++j)
        w2q[j] = *reinterpret_cast<const uint4*>(&wlds[OFF_W2 + g*56 + 4*j]);

    float kwr[4][9];
    #pragma unroll
    for (int k = 0; k < 9; ++k) {
        #pragma unroll
        for (int n = 0; n < 4; ++n) {
            h2 s = pk2(0.f, 0.f);
            #pragma unroll
            for (int m = 0; m < 3; ++m)
                #pragma unroll
                for (int rp = 0; rp < 2; ++rp) {
                    const int d = k*6 + 2*m + rp;
                    s = __builtin_elementwise_fma(tpk[n][m][rp],
                                                  u2h(GETW(w2q[d >> 2], d & 3)), s);
                }
            kwr[n][k] = (float)s.x + (float)s.y;
        }
    }
    #pragma unroll
    for (int n = 0; n < 4; ++n)
        #pragma unroll
        for (int k = 0; k < 9; ++k) {
            float v = kwr[n][k];
            v += __shfl_xor(v, 16);
            v += __shfl_xor(v, 32);
            kwr[n][k] = v + pw2_b[k];
        }

    // lane keeps slice n == g  ->  kw[9] for pixel 16g + c15 (+64w)
    float kw[9];
    #pragma unroll
    for (int k = 0; k < 9; ++k)
        kw[k] = (g == 0) ? kwr[0][k] : (g == 1) ? kwr[1][k] : (g == 2) ? kwr[2][k] : kwr[3][k];

    // ---- softmax over 9 ----
    float mx = kw[0];
    #pragma unroll
    for (int k = 1; k < 9; ++k) mx = fmaxf(mx, kw[k]);
    float sum = 0.f;
    #pragma unroll
    for (int k = 0; k < 9; ++k) { kw[k] = __expf(kw[k] - mx); sum += kw[k]; }
    const float inv = 1.f / sum;
    h2 kwp[9];
    #pragma unroll
    for (int k = 0; k < 9; ++k) { kw[k] *= inv; kwp[k] = pk2(kw[k], kw[k]); }

    // ---- pass 2: smoothing from the resident LDS tile ----
    const int sx = c15;
    const int sy = g + 4*w;
    const unsigned short* lb = &lx[(sy * LROW + sx) * CPAD];
    float* __restrict__ ob = out + (size_t)b * Cc * HWsz + (size_t)(y0 + sy) * Ww + (x0 + sx);
    #pragma unroll 2
    for (int cg = 0; cg < 12; ++cg) {
        const int c0 = cg * 8;
        uint4 tp[9];
        #pragma unroll
        for (int k = 0; k < 9; ++k) {
            const int dy = k / 3, dx = k - 3 * dy;
            tp[k] = *reinterpret_cast<const uint4*>(&lb[(dy*LROW + dx)*CPAD + c0]);
        }
        #pragma unroll
        for (int l = 0; l < 4; ++l) {
            h2 a0 = u2h(GETW(tp[0], l)) * kwp[0];
            h2 a1 = u2h(GETW(tp[1], l)) * kwp[1];
            h2 a2 = u2h(GETW(tp[2], l)) * kwp[2];
            a0 = __builtin_elementwise_fma(u2h(GETW(tp[3], l)), kwp[3], a0);
            a1 = __builtin_elementwise_fma(u2h(GETW(tp[4], l)), kwp[4], a1);
            a2 = __builtin_elementwise_fma(u2h(GETW(tp[5], l)), kwp[5], a2);
            a0 = __builtin_elementwise_fma(u2h(GETW(tp[6], l)), kwp[6], a0);
            a1 = __builtin_elementwise_fma(u2h(GETW(tp[7], l)), kwp[7], a1);
            a2 = __builtin_elementwise_fma(u2h(GETW(tp[8], l)), kwp[8], a2);
            float olo = (float)a0.x + (float)a1.x + (float)a2.x;
            float ohi = (float)a0.y + (float)a1.y + (float)a2.y;
            ob[(size_t)(c0 + 2*l)     * HWsz] = olo;
            ob[(size_t)(c0 + 2*l + 1) * HWsz] = ohi;
        }
    }
}

extern "C" void kernel_launch(void* const* d_in, const int* in_sizes, int n_in,
                              void* d_out, int out_size, void* d_ws, size_t ws_size,
                              hipStream_t stream)
{
    const float* x     = (const float*)d_in[0];
    const float* dw_w  = (const float*)d_in[1];
    const float* dw_b  = (const float*)d_in[2];
    const float* pw1_w = (const float*)d_in[3];
    const float* pw1_b = (const float*)d_in[4];
    const float* pw2_w = (const float*)d_in[5];
    const float* pw2_b = (const float*)d_in[6];
    float* outp = (float*)d_out;
    unsigned* wpk = (unsigned*)d_ws;

    alpf_prep<<<(NPK + 255) / 256, 256, 0, stream>>>(dw_w, dw_b, pw1_w, pw1_b, pw2_w, wpk);

    const int B = in_sizes[0] / (Cc * HWsz);   // 8
    dim3 grid((Ww / TW) * (Hh / TH) * B);      // 1024, 1D for swizzle control
    alpf_fused<<<grid, 128, 0, stream>>>(x, pw2_b, wpk, outp);
}

// Round 10
// 38.251 us; speedup vs baseline: 2.3444x; 1.0232x over previous
//
#include <hip/hip_runtime.h>
#include <math.h>

#define Cc 96
#define Hh 128
#define Ww 128
#define HWsz (Hh*Ww)
#define TW 16
#define TH 8
#define LROW 18
#define LPLANE 180
#define CPAD 104      // ushort stride per position: 208B rows, 16B-aligned

typedef _Float16 h2 __attribute__((ext_vector_type(2)));
typedef short    s8v __attribute__((ext_vector_type(8)));   // 8 bf16 (MFMA A/B frag)
typedef float    f4v __attribute__((ext_vector_type(4)));   // MFMA C/D frag

__device__ __forceinline__ unsigned pkrtz_u(float a, float b) {
    return __builtin_bit_cast(unsigned, __builtin_amdgcn_cvt_pkrtz(a, b));
}
__device__ __forceinline__ h2 pk2(float a, float b) {
    return __builtin_bit_cast(h2, __builtin_amdgcn_cvt_pkrtz(a, b));
}
__device__ __forceinline__ h2 u2h(unsigned u) { return __builtin_bit_cast(h2, u); }
__device__ __forceinline__ unsigned cvt_pk_bf16(float lo, float hi) {
    unsigned r;
    asm("v_cvt_pk_bf16_f32 %0, %1, %2" : "=v"(r) : "v"(lo), "v"(hi));
    return r;
}

__host__ __device__ __forceinline__ unsigned f2bf(float f) {   // fp32 -> bf16 RNE
    unsigned u = __float_as_uint(f);
    return (u + 0x7fffu + ((u >> 16) & 1u)) >> 16;
}

#define GETW(v, wi) ((wi)==0 ? (v).x : (wi)==1 ? (v).y : (wi)==2 ? (v).z : (v).w)

// ---- d_ws layout (dword offsets) ----
#define OFF_WDW 0
#define OFF_W2  480
#define OFF_P1B 704
#define OFF_A   768
#define NPK     3072
#define WLDS_N  752

__global__ void alpf_prep(const float* __restrict__ dw_w, const float* __restrict__ dw_b,
                          const float* __restrict__ pw1_w, const float* __restrict__ pw1_b,
                          const float* __restrict__ pw2_w, unsigned* __restrict__ wpk)
{
    int i = blockIdx.x * 256 + threadIdx.x;
    if (i >= NPK) return;
    unsigned v = 0u;
    if (i < OFF_W2) {
        int g = i / 120, rem = i % 120, ks = rem / 40, s = rem % 40;
        int chb = 32*ks + 8*g;
        if (s < 4) v = pkrtz_u(dw_b[chb + 2*s], dw_b[chb + 2*s + 1]);
        else { int t = (s - 4) / 4, d = (s - 4) % 4;
               v = pkrtz_u(dw_w[(chb + 2*d)*9 + t], dw_w[(chb + 2*d + 1)*9 + t]); }
    } else if (i < OFF_P1B) {
        int idx = i - OFF_W2; int g = idx / 56, s = idx % 56;
        if (s < 54) { int k = s / 6, mm = s % 6, m = mm / 2, rp = mm % 2;
            int o = 16*m + 4*g + 2*rp;
            v = pkrtz_u(pw2_w[k*48 + o], pw2_w[k*48 + o + 1]); }
    } else if (i < OFF_P1B + 48) {
        v = __float_as_uint(pw1_b[i - OFF_P1B]);
    } else if (i >= OFF_A) {
        int idx = i - OFF_A; int f = idx / 256, rem = idx % 256, l = rem / 4, d = rem % 4;
        int m = f / 3, ks = f % 3;
        int o  = 16*m + (l & 15);
        int ch = 32*ks + 8*(l >> 4) + 2*d;
        v = f2bf(pw1_w[o*Cc + ch]) | (f2bf(pw1_w[o*Cc + ch + 1]) << 16);
    }
    wpk[i] = v;
}

__global__ __launch_bounds__(256, 4)
void alpf_fused(const float* __restrict__ x,
                const float* __restrict__ pw2_b,
                const unsigned* __restrict__ wpk,
                float* __restrict__ out)
{
    __shared__ unsigned short lx[LPLANE * CPAD];   // 37440 B
    __shared__ unsigned wlds[WLDS_N];              // 3008 B weight cache

    const int tid = threadIdx.x;

    // ---- XCD-chunked swizzle (bijective: nwg = 1024, divisible by 8) ----
    const int nwg   = gridDim.x;
    const int chunk = nwg >> 3;
    const int logical = (blockIdx.x & 7) * chunk + (blockIdx.x >> 3);
    const int tx = logical & 7;             // 8 tiles in x
    const int ty = (logical >> 3) & 15;     // 16 tiles in y
    const int b  = logical >> 7;            // batch
    const int x0 = tx * TW;
    const int y0 = ty * TH;
    const float* __restrict__ xb = x + (size_t)b * Cc * HWsz;

    // ---- weight cache copy (752 dwords = 188 uint4) ----
    if (tid < 188)
        *reinterpret_cast<uint4*>(&wlds[tid * 4]) =
            *reinterpret_cast<const uint4*>(wpk + tid * 4);

    const int lane = tid & 63;
    const int g    = lane >> 4;
    const int c15  = lane & 15;
    const int wv   = tid >> 6;              // 0..3

    // ---- resident W1 A-fragments (loaded once, 36 VGPRs) ----
    s8v Af[9];
    #pragma unroll
    for (int f = 0; f < 9; ++f)
        Af[f] = __builtin_bit_cast(s8v,
            *reinterpret_cast<const uint4*>(wpk + OFF_A + (f*64 + lane)*4));

    // ---- staging: one halo slot per thread (tid < 180), all 12 cg ----
    if (tid < LPLANE) {
        const int r1 = tid / LROW, q1 = tid - r1 * LROW;
        const int gy1 = y0 - 1 + r1, gx1 = x0 - 1 + q1;
        const bool ok1 = (gy1 >= 0) & (gy1 < Hh) & (gx1 >= 0) & (gx1 < Ww);
        const int g1 = gy1 * Ww + gx1;
        #pragma unroll 2
        for (int cg = 0; cg < 12; ++cg) {
            const int c0 = cg * 8;
            const float* xc = xb + (size_t)c0 * HWsz;
            float v0 = ok1 ? xc[0*HWsz + g1] : 0.f;
            float v1 = ok1 ? xc[1*HWsz + g1] : 0.f;
            float v2_ = ok1 ? xc[2*HWsz + g1] : 0.f;
            float v3 = ok1 ? xc[3*HWsz + g1] : 0.f;
            float v4 = ok1 ? xc[4*HWsz + g1] : 0.f;
            float v5 = ok1 ? xc[5*HWsz + g1] : 0.f;
            float v6 = ok1 ? xc[6*HWsz + g1] : 0.f;
            float v7 = ok1 ? xc[7*HWsz + g1] : 0.f;
            *reinterpret_cast<uint4*>(&lx[tid * CPAD + c0]) =
                make_uint4(pkrtz_u(v0,v1), pkrtz_u(v2_,v3), pkrtz_u(v4,v5), pkrtz_u(v6,v7));
        }
    }
    __syncthreads();

    // ---- pw1 bias -> accumulators (D rows: o = 16m + 4g + r); wave owns rows 2wv, 2wv+1 ----
    f4v acc[3][2];
    #pragma unroll
    for (int m = 0; m < 3; ++m) {
        const f4v bb = *reinterpret_cast<const f4v*>(&wlds[OFF_P1B + 16*m + 4*g]);
        acc[m][0] = bb;
        acc[m][1] = bb;
    }

    // ---- depthwise conv (f16) -> bf16 B-frags -> MFMA pw1 ----
    #pragma unroll
    for (int ks = 0; ks < 3; ++ks) {
        const int base = (g*3 + ks) * 40;
        const uint4 wb = *reinterpret_cast<const uint4*>(&wlds[base]);
        uint4 wt[9];
        #pragma unroll
        for (int t = 0; t < 9; ++t)
            wt[t] = *reinterpret_cast<const uint4*>(&wlds[base + 4 + 4*t]);
        #pragma unroll
        for (int n = 0; n < 2; ++n) {
            h2 b0 = u2h(wb.x), b1 = u2h(wb.y), b2 = u2h(wb.z), b3 = u2h(wb.w);
            #pragma unroll
            for (int t = 0; t < 9; ++t) {
                const int dy = t / 3, dx = t - 3*dy;
                const uint4 xv = *reinterpret_cast<const uint4*>(
                    &lx[((2*wv + n + dy)*LROW + c15 + dx)*CPAD + 32*ks + 8*g]);
                b0 = __builtin_elementwise_fma(u2h(xv.x), u2h(wt[t].x), b0);
                b1 = __builtin_elementwise_fma(u2h(xv.y), u2h(wt[t].y), b1);
                b2 = __builtin_elementwise_fma(u2h(xv.z), u2h(wt[t].z), b2);
                b3 = __builtin_elementwise_fma(u2h(xv.w), u2h(wt[t].w), b3);
            }
            uint4 bq;
            bq.x = cvt_pk_bf16((float)b0.x, (float)b0.y);
            bq.y = cvt_pk_bf16((float)b1.x, (float)b1.y);
            bq.z = cvt_pk_bf16((float)b2.x, (float)b2.y);
            bq.w = cvt_pk_bf16((float)b3.x, (float)b3.y);
            const s8v Bf = __builtin_bit_cast(s8v, bq);
            acc[0][n] = __builtin_amdgcn_mfma_f32_16x16x32_bf16(Af[0 + ks], Bf, acc[0][n], 0, 0, 0);
            acc[1][n] = __builtin_amdgcn_mfma_f32_16x16x32_bf16(Af[3 + ks], Bf, acc[1][n], 0, 0, 0);
            acc[2][n] = __builtin_amdgcn_mfma_f32_16x16x32_bf16(Af[6 + ks], Bf, acc[2][n], 0, 0, 0);
        }
    }

    // ---- LeakyReLU + pack t to f16 pairs (o = 16m+4g+2rp, +1) ----
    h2 tpk[2][3][2];
    #pragma unroll
    for (int n = 0; n < 2; ++n)
        #pragma unroll
        for (int m = 0; m < 3; ++m)
            #pragma unroll
            for (int rp = 0; rp < 2; ++rp) {
                float a = acc[m][n][2*rp], c = acc[m][n][2*rp + 1];
                a = (a >= 0.f) ? a : 0.2f * a;
                c = (c >= 0.f) ? c : 0.2f * c;
                tpk[n][m][rp] = pk2(a, c);
            }

    // ---- pw2 partials (this lane's o-slice), then butterfly over g ----
    uint4 w2q[14];
    #pragma unroll
    for (int j = 0; j < 14; ++j)
        w2q[j] = *reinterpret_cast<const uint4*>(&wlds[OFF_W2 + g*56 + 4*j]);

    float kwr[2][9];
    #pragma unroll
    for (int k = 0; k < 9; ++k) {
        #pragma unroll
        for (int n = 0; n < 2; ++n) {
            h2 s = pk2(0.f, 0.f);
            #pragma unroll
            for (int m = 0; m < 3; ++m)
                #pragma unroll
                for (int rp = 0; rp < 2; ++rp) {
                    const int d = k*6 + 2*m + rp;
                    s = __builtin_elementwise_fma(tpk[n][m][rp],
                                                  u2h(GETW(w2q[d >> 2], d & 3)), s);
                }
            kwr[n][k] = (float)s.x + (float)s.y;
        }
    }
    #pragma unroll
    for (int n = 0; n < 2; ++n)
        #pragma unroll
        for (int k = 0; k < 9; ++k) {
            float v = kwr[n][k];
            v += __shfl_xor(v, 16);
            v += __shfl_xor(v, 32);
            kwr[n][k] = v + pw2_b[k];
        }

    // ---- pass 2 mapping: lane = 2 rows x 16 cols x 2 channel-halves ----
    const int nn  = (lane >> 4) & 1;        // row within wave's pair
    const int chh = lane >> 5;              // channel half (0: ch 0-47, 1: ch 48-95)
    const int row = 2*wv + nn;

    float kw[9];
    #pragma unroll
    for (int k = 0; k < 9; ++k) kw[k] = nn ? kwr[1][k] : kwr[0][k];

    // ---- softmax over 9 ----
    float mx = kw[0];
    #pragma unroll
    for (int k = 1; k < 9; ++k) mx = fmaxf(mx, kw[k]);
    float sum = 0.f;
    #pragma unroll
    for (int k = 0; k < 9; ++k) { kw[k] = __expf(kw[k] - mx); sum += kw[k]; }
    const float inv = 1.f / sum;
    h2 kwp[9];
    #pragma unroll
    for (int k = 0; k < 9; ++k) { kw[k] *= inv; kwp[k] = pk2(kw[k], kw[k]); }

    // ---- pass 2: smoothing; this lane covers 48 channels of its pixel ----
    const unsigned short* lb = &lx[(row * LROW + c15) * CPAD];
    float* __restrict__ ob = out + (size_t)b * Cc * HWsz + (size_t)(y0 + row) * Ww + (x0 + c15);
    #pragma unroll 2
    for (int cg = 0; cg < 6; ++cg) {
        const int c0 = chh * 48 + cg * 8;
        uint4 tp[9];
        #pragma unroll
        for (int k = 0; k < 9; ++k) {
            const int dy = k / 3, dx = k - 3 * dy;
            tp[k] = *reinterpret_cast<const uint4*>(&lb[(dy*LROW + dx)*CPAD + c0]);
        }
        #pragma unroll
        for (int l = 0; l < 4; ++l) {
            h2 a0 = u2h(GETW(tp[0], l)) * kwp[0];
            h2 a1 = u2h(GETW(tp[1], l)) * kwp[1];
            h2 a2 = u2h(GETW(tp[2], l)) * kwp[2];
            a0 = __builtin_elementwise_fma(u2h(GETW(tp[3], l)), kwp[3], a0);
            a1 = __builtin_elementwise_fma(u2h(GETW(tp[4], l)), kwp[4], a1);
            a2 = __builtin_elementwise_fma(u2h(GETW(tp[5], l)), kwp[5], a2);
            a0 = __builtin_elementwise_fma(u2h(GETW(tp[6], l)), kwp[6], a0);
            a1 = __builtin_elementwise_fma(u2h(GETW(tp[7], l)), kwp[7], a1);
            a2 = __builtin_elementwise_fma(u2h(GETW(tp[8], l)), kwp[8], a2);
            float olo = (float)a0.x + (float)a1.x + (float)a2.x;
            float ohi = (float)a0.y + (float)a1.y + (float)a2.y;
            ob[(size_t)(c0 + 2*l)     * HWsz] = olo;
            ob[(size_t)(c0 + 2*l + 1) * HWsz] = ohi;
        }
    }
}

extern "C" void kernel_launch(void* const* d_in, const int* in_sizes, int n_in,
                              void* d_out, int out_size, void* d_ws, size_t ws_size,
                              hipStream_t stream)
{
    const float* x     = (const float*)d_in[0];
    const float* dw_w  = (const float*)d_in[1];
    const float* dw_b  = (const float*)d_in[2];
    const float* pw1_w = (const float*)d_in[3];
    const float* pw1_b = (const float*)d_in[4];
    const float* pw2_w = (const float*)d_in[5];
    const float* pw2_b = (const float*)d_in[6];
    float* outp = (float*)d_out;
    unsigned* wpk = (unsigned*)d_ws;

    alpf_prep<<<(NPK + 255) / 256, 256, 0, stream>>>(dw_w, dw_b, pw1_w, pw1_b, pw2_w, wpk);

    const int B = in_sizes[0] / (Cc * HWsz);   // 8
    dim3 grid((Ww / TW) * (Hh / TH) * B);      // 1024 tiles, 1D for swizzle control
    alpf_fused<<<grid, 256, 0, stream>>>(x, pw2_b, wpk, outp);
}